// Round 7
// baseline (11869.022 us; speedup 1.0000x reference)
//
#include <hip/hip_runtime.h>
#include <hip/hip_cooperative_groups.h>
#include <math.h>

namespace cg = cooperative_groups;

#define BB 64
#define TT 512
#define FF 512
#define HH 1024
#define NG 4096  // 4H
#define NWG 64   // barrier participants

typedef _Float16 half8 __attribute__((ext_vector_type(8)));
typedef float f32x4 __attribute__((ext_vector_type(4)));

__device__ __forceinline__ float sigm(float x) { return 1.0f / (1.0f + __expf(-x)); }
__device__ __forceinline__ float tanh_fast(float x) {
    x = fminf(fmaxf(x, -30.0f), 30.0f);
    float e = __expf(2.0f * x);
    return (e - 1.0f) / (e + 1.0f);
}

// ---------------------------------------------------------------------------
// x fp32 -> f16, same [B,T,F] layout. 32 MiB into ws.
// ---------------------------------------------------------------------------
__global__ __launch_bounds__(256) void cvt_x(const float* __restrict__ x,
                                             _Float16* __restrict__ x16)
{
    size_t i = ((size_t)blockIdx.x * 256 + threadIdx.x) * 8;
    float4 a = *(const float4*)(x + i);
    float4 b = *(const float4*)(x + i + 4);
    half8 v;
    v[0] = (_Float16)a.x; v[1] = (_Float16)a.y; v[2] = (_Float16)a.z; v[3] = (_Float16)a.w;
    v[4] = (_Float16)b.x; v[5] = (_Float16)b.y; v[6] = (_Float16)b.z; v[7] = (_Float16)b.w;
    *(half8*)(x16 + i) = v;
}

// ---------------------------------------------------------------------------
// Persistent recurrence. 64 wgs x 1024 threads (16 waves: 4 rowgrps x 4 gates).
// wg = colgrp: owns h-cols [colgrp*16,+16) -> 64 gemm cols. Full batch (64).
// W_HH slice in dynamic LDS (129 KB). W_XH B-frags in registers (16 half8).
// h double-buffer inside d_out. h stores: agent-scope write-through atomics
// (no release fence needed). h loads: NORMAL cached loads; one acquire
// buffer_inv per step (tag-only: write-through means no dirty lines).
// Barrier: 64 flags; arrive = 1 relaxed store; wait = wave0 polls all 64
// flags with ONE coalesced load per round.
// MODE 0: x16 in ws.  MODE 1: fp32 x inline-cvt.  MODE 2: cg::grid.sync.
// ---------------------------------------------------------------------------
template<int MODE>
__global__ __launch_bounds__(1024, 1) void lstm_rec(
    const float* __restrict__ x, const float* __restrict__ w_xh,
    const float* __restrict__ w_hh, const float* __restrict__ bias,
    const float* __restrict__ scale, const float* __restrict__ offs,
    const float* __restrict__ pmean, const float* __restrict__ pvar,
    const _Float16* __restrict__ x16, int* flags, float* __restrict__ out)
{
    constexpr int KPH = HH + 8;   // f16 row stride 2064 B -> 2-way max aliasing (free)
    constexpr int GP  = 68;       // gbuf pitch (floats)
    extern __shared__ char smem[];
    _Float16* whh_l  = (_Float16*)smem;                       // 64*1032*2 = 132096 B
    float*    bias_l = (float*)(smem + 132096);               // 256 B
    float*    gbuf   = (float*)(smem + 132096 + 256);         // 64*68*4 = 17408 B
                                                              // total 149760 B
    const int wg  = blockIdx.x;          // = colgrp, 0..63
    const int tid = threadIdx.x;         // 0..1023
    const int lane = tid & 63, w = tid >> 6;     // wave 0..15
    const int wr = w >> 2, g = w & 3;            // row-group, gate
    const int q = lane >> 4, r = lane & 15;
    const int arow = wr * 16 + r;                // A-frag batch row

    // one-time: W_HH slice (64 gemm cols) -> LDS f16
    for (int idx = tid; idx < 64 * HH; idx += 1024) {
        int n = idx & 63, k = idx >> 6;
        int col = (n >> 4) * HH + wg * 16 + (n & 15);
        whh_l[n * KPH + k] = (_Float16)w_hh[(size_t)k * NG + col];
    }
    if (tid < 64) bias_l[tid] = bias[(tid >> 4) * HH + wg * 16 + (tid & 15)];

    // one-time: W_XH B-frags in registers. Wave (wr,g): col = g*H + wg*16 + r.
    half8 bx[16];
    {
        const int col = g * HH + wg * 16 + r;
        #pragma unroll
        for (int kk = 0; kk < 16; ++kk)
            #pragma unroll
            for (int j = 0; j < 8; ++j)
                bx[kk][j] = (_Float16)w_xh[(size_t)(kk * 32 + q * 8 + j) * NG + col];
    }

    _Float16* hbuf = (_Float16*)out;     // buf0=[0,64K) buf1=[64K,128K) f16
    const int m = tid >> 4, cl = tid & 15;       // epilogue: (batch row m, local col cl)
    const int hcol = wg * 16 + cl;
    if ((cl & 1) == 0)                   // zero h buf0, write-through to LLC
        __hip_atomic_store((unsigned*)(hbuf + m * HH + hcol), 0u,
                           __ATOMIC_RELAXED, __HIP_MEMORY_SCOPE_AGENT);

    cg::grid_group grid = cg::this_grid();

    // step-0 BN params
    float bnmu  = pmean[hcol];
    float bniss = scale[hcol] * rsqrtf(pvar[hcol] + 1e-5f);
    float bnoff = offs[hcol];

    // x-GEMM: A from x16 (or fp32 x), B from registers. Independent of h.
    auto xgemm = [&](int t) -> f32x4 {
        f32x4 a4 = {0.0f, 0.0f, 0.0f, 0.0f};
        if constexpr (MODE == 0) {
            const _Float16* xr = x16 + ((size_t)arow * TT + t) * FF;
            #pragma unroll
            for (int kk = 0; kk < 16; ++kk) {
                half8 a = *(const half8*)(xr + kk * 32 + q * 8);
                a4 = __builtin_amdgcn_mfma_f32_16x16x32_f16(a, bx[kk], a4, 0, 0, 0);
            }
        } else {
            const float* xr = x + ((size_t)arow * TT + t) * FF;
            #pragma unroll
            for (int kk = 0; kk < 16; ++kk) {
                int kb = kk * 32 + q * 8;
                float4 x0 = *(const float4*)(xr + kb);
                float4 x1 = *(const float4*)(xr + kb + 4);
                half8 a;
                a[0] = (_Float16)x0.x; a[1] = (_Float16)x0.y;
                a[2] = (_Float16)x0.z; a[3] = (_Float16)x0.w;
                a[4] = (_Float16)x1.x; a[5] = (_Float16)x1.y;
                a[6] = (_Float16)x1.z; a[7] = (_Float16)x1.w;
                a4 = __builtin_amdgcn_mfma_f32_16x16x32_f16(a, bx[kk], a4, 0, 0, 0);
            }
        }
        return a4;
    };

    int ep = 1;
    __syncthreads();                     // drains vmcnt: zeros + LDS staged
    if constexpr (MODE == 2) { grid.sync(); }
    else if (tid == 0)
        __hip_atomic_store(&flags[wg], ep, __ATOMIC_RELAXED, __HIP_MEMORY_SCOPE_AGENT);

    f32x4 xacc = xgemm(0);

    if constexpr (MODE != 2) {
        if (tid < 64) {
            while (__hip_atomic_load(&flags[lane], __ATOMIC_RELAXED,
                                     __HIP_MEMORY_SCOPE_AGENT) < ep)
                __builtin_amdgcn_s_sleep(2);
        }
        if (tid == 0) __builtin_amdgcn_fence(__ATOMIC_ACQUIRE, "agent");
        __syncthreads();
    }
    ++ep;

    float c_reg = 0.0f, h_out = 0.0f;
    int cur = 0;

    for (int t = 0; t < TT; ++t) {
        f32x4 acc = xacc;

        // h-GEMM: A = h rows [wr*16,+16) normal cached loads (L1/L2 dedup the
        // 4-waves-same-rows overlap); B = whh_l. K=1024 -> 32 MFMAs.
        const _Float16* hrow = hbuf + (size_t)cur * (BB * HH) + (size_t)arow * HH;
        const _Float16* brow = &whh_l[(g * 16 + r) * KPH];
        #pragma unroll
        for (int kk = 0; kk < 32; ++kk) {
            half8 a = *(const half8*)(hrow + kk * 32 + q * 8);
            half8 b = *(const half8*)(brow + kk * 32 + q * 8);
            acc = __builtin_amdgcn_mfma_f32_16x16x32_f16(a, b, acc, 0, 0, 0);
        }

        // C layout: row = wr*16 + q*4+reg, col = g*16 + r
        #pragma unroll
        for (int reg = 0; reg < 4; ++reg)
            gbuf[(wr * 16 + q * 4 + reg) * GP + g * 16 + r] = acc[reg];
        __syncthreads();

        // cell update: thread (m, cl) owns (m, hcol)
        float f_ = gbuf[m * GP +  0 + cl] + bias_l[ 0 + cl];
        float i_ = gbuf[m * GP + 16 + cl] + bias_l[16 + cl];
        float o_ = gbuf[m * GP + 32 + cl] + bias_l[32 + cl];
        float g_ = gbuf[m * GP + 48 + cl] + bias_l[48 + cl];
        c_reg = sigm(f_ + 1.0f) * c_reg + sigm(i_) * tanh_fast(g_);
        float cn = (c_reg - bnmu) * bniss + bnoff;
        h_out = sigm(o_) * tanh_fast(cn);

        // pack f16 pair across cl^1, write-through to LLC (4-B atomic)
        {
            unsigned short hb = __builtin_bit_cast(unsigned short, (_Float16)h_out);
            unsigned short pb = (unsigned short)__shfl_xor((int)hb, 1, 64);
            if ((cl & 1) == 0) {
                unsigned packed = (unsigned)hb | ((unsigned)pb << 16);
                __hip_atomic_store(
                    (unsigned*)(hbuf + (size_t)(cur ^ 1) * (BB * HH) + m * HH + hcol),
                    packed, __ATOMIC_RELAXED, __HIP_MEMORY_SCOPE_AGENT);
            }
        }

        // prefetch next BN params (h-independent)
        if (t + 1 < TT) {
            bnmu  = pmean[(t + 1) * HH + hcol];
            bniss = scale[(t + 1) * HH + hcol] * rsqrtf(pvar[(t + 1) * HH + hcol] + 1e-5f);
            bnoff = offs [(t + 1) * HH + hcol];
        }

        __syncthreads();   // all waves drain vmcnt: h stores at LLC; gbuf reads done
        if constexpr (MODE == 2) {
            if (t + 1 < TT) xacc = xgemm(t + 1);
            grid.sync();
        } else {
            if (tid == 0)
                __hip_atomic_store(&flags[wg], ep, __ATOMIC_RELAXED, __HIP_MEMORY_SCOPE_AGENT);
            if (t + 1 < TT) xacc = xgemm(t + 1);   // hidden under flag propagation
            if (tid < 64) {
                while (__hip_atomic_load(&flags[lane], __ATOMIC_RELAXED,
                                         __HIP_MEMORY_SCOPE_AGENT) < ep)
                    __builtin_amdgcn_s_sleep(2);
            }
            if (tid == 0) __builtin_amdgcn_fence(__ATOMIC_ACQUIRE, "agent");
            __syncthreads();
        }
        ++ep;
        cur ^= 1;
    }

    // after final barrier nobody reads hbuf -> overwrite with fp32 output
    out[m * HH + hcol] = h_out;
}

extern "C" void kernel_launch(void* const* d_in, const int* in_sizes, int n_in,
                              void* d_out, int out_size, void* d_ws, size_t ws_size,
                              hipStream_t stream) {
    const float* x     = (const float*)d_in[0];
    const float* w_xh  = (const float*)d_in[1];
    const float* w_hh  = (const float*)d_in[2];
    const float* bias  = (const float*)d_in[3];
    const float* scale = (const float*)d_in[4];
    const float* offs  = (const float*)d_in[5];
    const float* pmean = (const float*)d_in[6];
    const float* pvar  = (const float*)d_in[7];
    float* out = (float*)d_out;

    int* flags = (int*)d_ws;                          // 256 B
    _Float16* x16 = (_Float16*)((char*)d_ws + 4096);  // 32 MiB
    const size_t X16B = (size_t)BB * TT * FF * 2;
    const int mode = (ws_size >= X16B + 4096) ? 0 : (ws_size >= 2048 ? 1 : 2);

    if (mode <= 1) (void)hipMemsetAsync(d_ws, 0, 2048, stream);
    if (mode == 0) {
        const size_t nelem = (size_t)BB * TT * FF;
        cvt_x<<<dim3((unsigned)(nelem / (256 * 8))), 256, 0, stream>>>(x, x16);
    }

    const uint32_t shmem = 132096 + 256 + 17408;   // 149760 B
    const void* f = (mode == 0) ? (const void*)&lstm_rec<0>
                  : (mode == 1) ? (const void*)&lstm_rec<1>
                                : (const void*)&lstm_rec<2>;
    (void)hipFuncSetAttribute(f, hipFuncAttributeMaxDynamicSharedMemorySize, (int)shmem);

    void* args[] = {&x, &w_xh, &w_hh, &bias, &scale, &offs, &pmean, &pvar,
                    &x16, &flags, &out};
    (void)hipLaunchCooperativeKernel(f, dim3(NWG), dim3(1024), args, shmem, stream);
}

// Round 8
// 5885.394 us; speedup vs baseline: 2.0167x; 2.0167x over previous
//
#include <hip/hip_runtime.h>
#include <math.h>

#define BB 64
#define TT 512
#define FF 512
#define HH 1024
#define NG 4096   // 4H
#define NCON 32   // consumer wgs (recurrence)
#define NPROD 224 // producer wgs (x-projection)
#define RING 60   // xp ring slots (60*512KB = 30.7 MB ws)

typedef _Float16 half8 __attribute__((ext_vector_type(8)));
typedef float f32x4 __attribute__((ext_vector_type(4)));
typedef unsigned long long u64;

__device__ __forceinline__ float sigm(float x) { return 1.0f / (1.0f + __expf(-x)); }
__device__ __forceinline__ float tanh_fast(float x) {
    x = fminf(fmaxf(x, -30.0f), 30.0f);
    float e = __expf(2.0f * x);
    return (e - 1.0f) / (e + 1.0f);
}

// ---------------------------------------------------------------------------
// One persistent kernel, 256 wgs x 512 threads (1 wg/CU).
//  wg 0..31   : consumers — the 512-step recurrence.
//  wg 32..255 : producers — xp[t] = x_t @ W_XH into a 60-slot ring in ws,
//               running far ahead; release-fence(wbl2) + ready[t] publish.
// Consumer step: sc1 flag barrier (32 flags, one coalesced poll) ->
//   acquire-inv (cheap: W_HH in VGPRs, bias LDS, nothing hot cacheable) ->
//   stage h (128KB) to LDS -> 128 MFMA/wave from LDS A + VGPR B ->
//   gbuf -> cell update -> sc1 write-through h store.
// h double-buffer lives in d_out (2 * 64*1024 f16 == out_size*4 bytes).
// ---------------------------------------------------------------------------
__global__ __launch_bounds__(512, 2) void lstm_all(
    const float* __restrict__ x, const float* __restrict__ w_xh,
    const float* __restrict__ w_hh, const float* __restrict__ bias,
    const float* __restrict__ scale, const float* __restrict__ offs,
    const float* __restrict__ pmean, const float* __restrict__ pvar,
    int* ws_i, _Float16* ring, float* __restrict__ out)
{
    extern __shared__ char smem[];
    int* flags   = ws_i;          // [64] step flags (values t+1, final 600)
    int* conspub = ws_i + 64;     // consumer progress (ring guard)
    int* ready   = ws_i + 256;    // [512] xp slot ready

    const int wg = blockIdx.x, tid = threadIdx.x;
    const int lane = tid & 63, w = tid >> 6;      // wave 0..7
    const int q = lane >> 4, r = lane & 15;

    if (wg < NCON) {
        // ======================= CONSUMER =======================
        const int s = wg;                          // owns h-cols [s*32, s*32+32)
        _Float16* hlds  = (_Float16*)smem;         // [64][1032] staged h (132096 B)
        float*    gbuf  = (float*)smem;            // alias: [2][4][64][36] (73728 B)
        float*    bias_l = (float*)(smem + 132096);// [128]
        const int g = w >> 1, a = w & 1;           // wave = (gate, K-half)

        // one-time: W_HH B-fragments -> VGPRs (immune to per-step inv)
        half8 bfr[2][16];
        #pragma unroll
        for (int cb = 0; cb < 2; ++cb)
            #pragma unroll
            for (int kk = 0; kk < 16; ++kk)
                #pragma unroll
                for (int j = 0; j < 8; ++j) {
                    int k = a * 512 + kk * 32 + q * 8 + j;
                    bfr[cb][kk][j] =
                        (_Float16)w_hh[(size_t)k * NG + g * HH + s * 32 + cb * 16 + r];
                }
        if (tid < 128) bias_l[tid] = bias[(tid >> 5) * HH + s * 32 + (tid & 31)];

        _Float16* hbuf = (_Float16*)out;           // f16 double buffer in d_out
        const int m = tid >> 3, jj = (tid & 7) * 4;// epilogue owner: (row m, 4 cols)
        const int col0 = s * 32 + jj;
        // zero h buf0 slice, write-through to LLC
        __hip_atomic_store((u64*)(hbuf + m * HH + col0), 0ull,
                           __ATOMIC_RELAXED, __HIP_MEMORY_SCOPE_AGENT);

        f32x4 c_reg = {0, 0, 0, 0}, h_reg = {0, 0, 0, 0};
        int cur = 0;
        __syncthreads();                           // zeros drained (vmcnt)

        for (int t = 0; t < TT; ++t) {
            const int ep = t + 1;
            if (tid == 0)
                __hip_atomic_store(&flags[s], ep, __ATOMIC_RELAXED, __HIP_MEMORY_SCOPE_AGENT);
            if (tid < 64) {
                for (;;) {
                    int v;
                    if (lane < 32)
                        v = __hip_atomic_load(&flags[lane], __ATOMIC_RELAXED, __HIP_MEMORY_SCOPE_AGENT);
                    else if (lane == 32)
                        v = __hip_atomic_load(&ready[t], __ATOMIC_RELAXED, __HIP_MEMORY_SCOPE_AGENT) ? ep : 0;
                    else v = ep;
                    if (__all(v >= ep)) break;
                    __builtin_amdgcn_s_sleep(1);
                }
            }
            if (tid == 0) __builtin_amdgcn_fence(__ATOMIC_ACQUIRE, "agent"); // inv L1/L2
            __syncthreads();

            if (s == 0 && tid == 0 && t && (t & 7) == 0)   // ring guard publish
                __hip_atomic_store(conspub, t - 1, __ATOMIC_RELAXED, __HIP_MEMORY_SCOPE_AGENT);

            // xp (sc1, LLC) + BN for this step — latency hidden under stage/GEMM
            u64 xpv[4];
            const _Float16* rslot = ring + (size_t)(t % RING) * (BB * NG);
            #pragma unroll
            for (int gg = 0; gg < 4; ++gg)
                xpv[gg] = __hip_atomic_load((const u64*)(rslot + m * NG + gg * HH + col0),
                                            __ATOMIC_RELAXED, __HIP_MEMORY_SCOPE_AGENT);
            f32x4 mu = *(const f32x4*)(pmean + (size_t)t * HH + col0);
            f32x4 pv = *(const f32x4*)(pvar  + (size_t)t * HH + col0);
            f32x4 sc = *(const f32x4*)(scale + (size_t)t * HH + col0);
            f32x4 of = *(const f32x4*)(offs  + (size_t)t * HH + col0);

            // stage h -> LDS (pitch 1032 f16 = 2064 B, <=2-way banks)
            {
                const int row = tid >> 3, seg = tid & 7;
                const _Float16* gs = hbuf + (size_t)cur * (BB * HH) + row * HH + seg * 128;
                _Float16* ld = hlds + row * 1032 + seg * 128;
                #pragma unroll
                for (int i = 0; i < 16; ++i)
                    *(half8*)(ld + i * 8) = *(const half8*)(gs + i * 8);
            }
            __syncthreads();

            // h-GEMM: A from LDS, B from VGPRs. 128 MFMA/wave.
            f32x4 acc[4][2] = {};
            #pragma unroll
            for (int kk = 0; kk < 16; ++kk) {
                half8 af[4];
                #pragma unroll
                for (int rb = 0; rb < 4; ++rb)
                    af[rb] = *(const half8*)(hlds + (rb * 16 + r) * 1032 + a * 512 + kk * 32 + q * 8);
                #pragma unroll
                for (int rb = 0; rb < 4; ++rb) {
                    acc[rb][0] = __builtin_amdgcn_mfma_f32_16x16x32_f16(af[rb], bfr[0][kk], acc[rb][0], 0, 0, 0);
                    acc[rb][1] = __builtin_amdgcn_mfma_f32_16x16x32_f16(af[rb], bfr[1][kk], acc[rb][1], 0, 0, 0);
                }
            }
            __syncthreads();   // LDS h reads done -> reuse region as gbuf

            #pragma unroll
            for (int rb = 0; rb < 4; ++rb)
                #pragma unroll
                for (int cb = 0; cb < 2; ++cb)
                    #pragma unroll
                    for (int reg = 0; reg < 4; ++reg)
                        gbuf[((a * 4 + g) * 64 + rb * 16 + q * 4 + reg) * 36 + cb * 16 + r] = acc[rb][cb][reg];
            __syncthreads();

            // cell update: thread (m, jj) owns 4 h-cols
            f32x4 gv[4];
            #pragma unroll
            for (int gg = 0; gg < 4; ++gg) {
                f32x4 v0 = *(const f32x4*)&gbuf[((0 * 4 + gg) * 64 + m) * 36 + jj];
                f32x4 v1 = *(const f32x4*)&gbuf[((1 * 4 + gg) * 64 + m) * 36 + jj];
                f32x4 bi = *(const f32x4*)&bias_l[gg * 32 + jj];
                union { u64 u; _Float16 h[4]; } ux; ux.u = xpv[gg];
                f32x4 vv;
                #pragma unroll
                for (int j = 0; j < 4; ++j) vv[j] = v0[j] + v1[j] + bi[j] + (float)ux.h[j];
                gv[gg] = vv;
            }
            #pragma unroll
            for (int j = 0; j < 4; ++j) {
                float iss = sc[j] * rsqrtf(pv[j] + 1e-5f);
                c_reg[j] = sigm(gv[0][j] + 1.0f) * c_reg[j] + sigm(gv[1][j]) * tanh_fast(gv[3][j]);
                float cn = (c_reg[j] - mu[j]) * iss + of[j];
                h_reg[j] = sigm(gv[2][j]) * tanh_fast(cn);
            }
            if (t < TT - 1) {
                union { u64 u; unsigned short s4[4]; } ph;
                #pragma unroll
                for (int j = 0; j < 4; ++j)
                    ph.s4[j] = __builtin_bit_cast(unsigned short, (_Float16)h_reg[j]);
                __hip_atomic_store((u64*)(hbuf + (size_t)(cur ^ 1) * (BB * HH) + m * HH + col0),
                                   ph.u, __ATOMIC_RELAXED, __HIP_MEMORY_SCOPE_AGENT);
                __syncthreads();   // drain h stores + gbuf reads done
            } else {
                // final: all consumers must finish reading hbuf before fp32 overwrite
                __syncthreads();
                if (tid == 0)
                    __hip_atomic_store(&flags[s], 600, __ATOMIC_RELAXED, __HIP_MEMORY_SCOPE_AGENT);
                if (tid < 64) {
                    for (;;) {
                        int v = (lane < 32)
                            ? __hip_atomic_load(&flags[lane], __ATOMIC_RELAXED, __HIP_MEMORY_SCOPE_AGENT)
                            : 600;
                        if (__all(v >= 600)) break;
                        __builtin_amdgcn_s_sleep(1);
                    }
                }
                __syncthreads();
                *(f32x4*)(out + m * HH + col0) = h_reg;
            }
            cur ^= 1;
        }
    } else {
        // ======================= PRODUCER =======================
        const int p = wg - NCON;                    // 0..223
        _Float16* xs = (_Float16*)smem;             // [64][520] x_t f16 (66560 B)
        _Float16* bl = (_Float16*)(smem + 66560);   // [32][520] B chunk (33280 B)
        const int rb = w & 3, ch = (w >> 2) & 1;    // wave: rowblock x col-half

        for (int t = p; t < TT; t += NPROD) {
            if (t >= RING) {                        // ring-slot reuse guard
                if (tid == 0)
                    while (__hip_atomic_load(conspub, __ATOMIC_RELAXED, __HIP_MEMORY_SCOPE_AGENT) < t - (RING - 1))
                        __builtin_amdgcn_s_sleep(16);
                __syncthreads();
            }
            // stage x_t -> LDS f16
            {
                const int row = tid >> 3, seg = tid & 7;
                const float* xr = x + (size_t)row * (TT * FF) + (size_t)t * FF + seg * 64;
                #pragma unroll
                for (int i = 0; i < 16; ++i) {
                    float4 v = *(const float4*)(xr + i * 4);
                    _Float16* d = xs + row * 520 + seg * 64 + i * 4;
                    d[0] = (_Float16)v.x; d[1] = (_Float16)v.y;
                    d[2] = (_Float16)v.z; d[3] = (_Float16)v.w;
                }
            }
            _Float16* xpd = ring + (size_t)(t % RING) * (BB * NG);
            for (int it = 0; it < 128; ++it) {      // 32 cols per iter
                __syncthreads();                    // xs ready / prev bl reads done
                {
                    const int k = tid;              // K row of B chunk
                    const float* br = w_xh + (size_t)k * NG + it * 32;
                    #pragma unroll
                    for (int c4 = 0; c4 < 8; ++c4) {
                        float4 v = *(const float4*)(br + c4 * 4);
                        bl[(c4 * 4 + 0) * 520 + k] = (_Float16)v.x;
                        bl[(c4 * 4 + 1) * 520 + k] = (_Float16)v.y;
                        bl[(c4 * 4 + 2) * 520 + k] = (_Float16)v.z;
                        bl[(c4 * 4 + 3) * 520 + k] = (_Float16)v.w;
                    }
                }
                __syncthreads();
                f32x4 acc = {0, 0, 0, 0};
                #pragma unroll
                for (int kk = 0; kk < 16; ++kk) {
                    half8 av = *(const half8*)(xs + (rb * 16 + r) * 520 + kk * 32 + q * 8);
                    half8 bv = *(const half8*)(bl + (ch * 16 + r) * 520 + kk * 32 + q * 8);
                    acc = __builtin_amdgcn_mfma_f32_16x16x32_f16(av, bv, acc, 0, 0, 0);
                }
                const int colg = it * 32 + ch * 16 + r;
                #pragma unroll
                for (int reg = 0; reg < 4; ++reg)
                    xpd[(size_t)(rb * 16 + q * 4 + reg) * NG + colg] = (_Float16)acc[reg];
            }
            __syncthreads();
            if (tid == 0) {
                __builtin_amdgcn_fence(__ATOMIC_RELEASE, "agent");  // wbl2: xp -> LLC
                __hip_atomic_store(&ready[t], 1, __ATOMIC_RELAXED, __HIP_MEMORY_SCOPE_AGENT);
            }
        }
    }
}

extern "C" void kernel_launch(void* const* d_in, const int* in_sizes, int n_in,
                              void* d_out, int out_size, void* d_ws, size_t ws_size,
                              hipStream_t stream) {
    const float* x     = (const float*)d_in[0];
    const float* w_xh  = (const float*)d_in[1];
    const float* w_hh  = (const float*)d_in[2];
    const float* bias  = (const float*)d_in[3];
    const float* scale = (const float*)d_in[4];
    const float* offs  = (const float*)d_in[5];
    const float* pmean = (const float*)d_in[6];
    const float* pvar  = (const float*)d_in[7];
    float* out = (float*)d_out;

    int* ws_i = (int*)d_ws;                               // flags/conspub/ready in [0,4096)
    _Float16* ring = (_Float16*)((char*)d_ws + 8192);     // 60 * 512 KB = 30.7 MB

    (void)hipMemsetAsync(d_ws, 0, 4096, stream);

    const uint32_t shmem = 132608;   // max(consumer 132096+512, producer 99840)
    (void)hipFuncSetAttribute((const void*)&lstm_all,
                              hipFuncAttributeMaxDynamicSharedMemorySize, (int)shmem);

    void* args[] = {&x, &w_xh, &w_hh, &bias, &scale, &offs, &pmean, &pvar,
                    &ws_i, &ring, &out};
    (void)hipLaunchCooperativeKernel((const void*)&lstm_all, dim3(256), dim3(512),
                                     args, shmem, stream);
}